// Round 4
// baseline (875.852 us; speedup 1.0000x reference)
//
#include <hip/hip_runtime.h>

// HubnormTripletLoss, N=8192 — single fused persistent kernel.
// P = Sinkhorn(exp(-(1-s)/lamb), 5 iters) == P0 * R[i] * C[j] (diagonal scaling);
// global norm cancels in the first row step. Q = fp8-e4m3(P0) (64MB, L3-resident).
// Phases (grid-wide barriers between):
//   A      : quantize P0 -> Q, R = 1/rowsum(Q), diag -> Qd, zero CsA/out
//   colmvP : part[b][j] = sum_{rows of b} Q[i,j]*R[i]      (per-block partial)
//   colmvR : Cs[j] = sum_b part[b][j]                      (32-way atomic)
//   rowmv  : R[i] = 1/sum_j Q[i,j]*rcp(Cs[j])              (x4)
//   loss   : sum_{i!=j} hinge(P-d[j]) + hinge(P-d[i]),  d[k]=Qd[k]*R[k]*rcp(Cs[k])
// One dispatch: no launch/drain overhead, rows are block-local (block b owns
// rows [b*32, b*32+32) in every phase). Barrier = device-scope atomic counter,
// booted via magic-handshake (ws is poisoned 0xAA, so 0xC0FFEE != initial).

#define NN 8192u
#define MARGIN 0.2f
#define KF (1.4426950408889634f / 0.012f)  // log2(e)/lamb
#define NBLK 256u
#define NTHR 1024u

__device__ __forceinline__ float fexp2(float x) { return __builtin_amdgcn_exp2f(x); }
__device__ __forceinline__ float frcp(float x) { return __builtin_amdgcn_rcpf(x); }

__device__ __forceinline__ void unpk8(uint2 q, float* f) {
  auto a = __builtin_amdgcn_cvt_pk_f32_fp8((int)q.x, false);
  auto b = __builtin_amdgcn_cvt_pk_f32_fp8((int)q.x, true);
  auto c = __builtin_amdgcn_cvt_pk_f32_fp8((int)q.y, false);
  auto d = __builtin_amdgcn_cvt_pk_f32_fp8((int)q.y, true);
  f[0] = a[0]; f[1] = a[1]; f[2] = b[0]; f[3] = b[1];
  f[4] = c[0]; f[5] = c[1]; f[6] = d[0]; f[7] = d[1];
}

// grid barrier: leader fences (wbl2), arrives, spins at device scope, fences
// (invl2); other waves park at s_barrier. n must be identical across blocks.
__device__ __forceinline__ void gbarrier(uint* bar, uint n, uint tid) {
  __syncthreads();
  if (tid == 0) {
    __threadfence();
    atomicAdd(bar, 1u);
    const uint tgt = NBLK * n;
    while (atomicAdd(bar, 0u) < tgt) __builtin_amdgcn_s_sleep(8);
    __threadfence();
  }
  __syncthreads();
}

__global__ __launch_bounds__(NTHR) void k_fused(
    const float* __restrict__ sims, uint* __restrict__ Qw,
    float* __restrict__ part, float* __restrict__ R, float* __restrict__ CsA,
    float* __restrict__ CsB, float* __restrict__ Qd, uint* __restrict__ ctl,
    float* __restrict__ out) {
  const uint b = blockIdx.x, tid = threadIdx.x;
  const uint w = tid >> 6, lane = tid & 63u;
  __shared__ float red[512];  // [32 rows][16 waves]
  uint* ready = ctl;
  uint* bar = ctl + 1;

  // ---- boot: zero bar, publish via magic (ws poisoned 0xAA each launch) ----
  if (b == 0 && tid == 0) {
    atomicExch(bar, 0u);
    __threadfence();
    atomicExch(ready, 0xC0FFEEu);
  }
  if (b != 0 && tid == 0) {
    while (atomicAdd(ready, 0u) != 0xC0FFEEu) __builtin_amdgcn_s_sleep(8);
    __threadfence();
  }
  __syncthreads();
  uint bn = 0;

  // ---- phase A: quantize + rowsum (wave-per-row, 2 rows/wave) --------------
#pragma unroll
  for (uint q = 0; q < 2u; ++q) {
    const uint row = b * 32u + q * 16u + w;
    const uint dit = row >> 8, dl = (row >> 2) & 63u, sel = row & 3u;
    float acc = 0.f;
    for (uint it = 0; it < 32u; ++it) {
      const uint col = it * 256u + lane * 4u;
      const float4 s = *(const float4*)(sims + (size_t)row * NN + col);
      const float p0 = fexp2((s.x - 1.f) * KF);
      const float p1 = fexp2((s.y - 1.f) * KF);
      const float p2 = fexp2((s.z - 1.f) * KF);
      const float p3 = fexp2((s.w - 1.f) * KF);
      int pk = 0;
      pk = __builtin_amdgcn_cvt_pk_fp8_f32(p0, p1, pk, false);
      pk = __builtin_amdgcn_cvt_pk_fp8_f32(p2, p3, pk, true);
      Qw[((size_t)row * NN + col) >> 2] = (uint)pk;
      auto lo = __builtin_amdgcn_cvt_pk_f32_fp8(pk, false);
      auto hi = __builtin_amdgcn_cvt_pk_f32_fp8(pk, true);
      acc += (lo[0] + lo[1]) + (hi[0] + hi[1]);  // sum QUANTIZED values
      if (it == dit && lane == dl)
        Qd[row] = sel == 0u ? lo[0] : sel == 1u ? lo[1] : sel == 2u ? hi[0] : hi[1];
    }
#pragma unroll
    for (int o = 32; o; o >>= 1) acc += __shfl_down(acc, o, 64);
    if (lane == 0) R[row] = frcp(acc);
  }
  if (tid < 32u) CsA[b * 32u + tid] = 0.f;
  if (b == 0 && tid == 0) *out = 0.f;

  // ---- 5 Sinkhorn col steps, 4 row steps -----------------------------------
  for (uint k = 0; k < 5u; ++k) {
    float* dst = (k & 1u) ? CsB : CsA;
    float* oth = (k & 1u) ? CsA : CsB;
    gbarrier(bar, ++bn, tid);  // after A / after rowmv_{k-1}
    {  // colmv partial: rows [b*32,+32), thread cols [tid*8,+8)
      const uint j0 = tid * 8u;
      float a[8];
#pragma unroll
      for (int i = 0; i < 8; ++i) a[i] = 0.f;
      for (uint r = 0; r < 32u; ++r) {
        const uint row = b * 32u + r;
        const float Rr = R[row];  // block-uniform -> s_load
        const uint2 q2 = *(const uint2*)(Qw + (((size_t)row * NN + j0) >> 2));
        float f[8];
        unpk8(q2, f);
#pragma unroll
        for (int i = 0; i < 8; ++i) a[i] = fmaf(f[i], Rr, a[i]);
      }
      *(float4*)(part + (size_t)b * NN + j0) = make_float4(a[0], a[1], a[2], a[3]);
      *(float4*)(part + (size_t)b * NN + j0 + 4) = make_float4(a[4], a[5], a[6], a[7]);
    }
    gbarrier(bar, ++bn, tid);
    {  // reduce partials -> dst (32-way atomics, 8 partials per task)
      const uint g = b * NTHR + tid;
      const uint j = g & (NN - 1u);
      const uint c = g >> 13;  // 0..31
      float s = 0.f;
#pragma unroll
      for (uint r = 0; r < 8u; ++r) s += part[(size_t)(c * 8u + r) * NN + j];
      atomicAdd(dst + j, s);
    }
    gbarrier(bar, ++bn, tid);
    if (k < 4u) {  // rowmv: rows [b*32,+32), cinv in regs, no LDS staging
      const uint j0 = tid * 8u;
      const float4 c0 = *(const float4*)(dst + j0);
      const float4 c1 = *(const float4*)(dst + j0 + 4);
      float cinv[8] = {frcp(c0.x), frcp(c0.y), frcp(c0.z), frcp(c0.w),
                       frcp(c1.x), frcp(c1.y), frcp(c1.z), frcp(c1.w)};
      if (tid < 32u) oth[b * 32u + tid] = 0.f;  // zero next iter's dst
      for (uint r = 0; r < 32u; ++r) {
        const uint row = b * 32u + r;
        const uint2 q2 = *(const uint2*)(Qw + (((size_t)row * NN + j0) >> 2));
        float f[8];
        unpk8(q2, f);
        float s = f[0] * cinv[0] + f[1] * cinv[1] + f[2] * cinv[2] +
                  f[3] * cinv[3] + f[4] * cinv[4] + f[5] * cinv[5] +
                  f[6] * cinv[6] + f[7] * cinv[7];
#pragma unroll
        for (int o = 32; o; o >>= 1) s += __shfl_down(s, o, 64);
        if (lane == 0) red[r * 16u + w] = s;
      }
      __syncthreads();
      if (tid < 32u) {
        float s = 0.f;
#pragma unroll
        for (uint i = 0; i < 16u; ++i) s += red[tid * 16u + i];
        R[b * 32u + tid] = frcp(s);
      }
    }
  }

  // ---- loss (R final, Cs = CsA from k=4) -----------------------------------
  {
    const uint j0 = tid * 8u;
    const float4 c0 = *(const float4*)(CsA + j0);
    const float4 c1 = *(const float4*)(CsA + j0 + 4);
    const float4 r0 = *(const float4*)(R + j0);
    const float4 r1 = *(const float4*)(R + j0 + 4);
    const float4 q0 = *(const float4*)(Qd + j0);
    const float4 q1 = *(const float4*)(Qd + j0 + 4);
    float cinv[8] = {frcp(c0.x), frcp(c0.y), frcp(c0.z), frcp(c0.w),
                     frcp(c1.x), frcp(c1.y), frcp(c1.z), frcp(c1.w)};
    float dj[8] = {q0.x * r0.x * cinv[0], q0.y * r0.y * cinv[1],
                   q0.z * r0.z * cinv[2], q0.w * r0.w * cinv[3],
                   q1.x * r1.x * cinv[4], q1.y * r1.y * cinv[5],
                   q1.z * r1.z * cinv[6], q1.w * r1.w * cinv[7]};
    float acc = 0.f;
    for (uint r = 0; r < 32u; ++r) {
      const uint row = b * 32u + r;
      const float Rr = R[row];                          // uniform
      const float drow = Qd[row] * Rr * frcp(CsA[row]); // uniform
      const uint2 q2 = *(const uint2*)(Qw + (((size_t)row * NN + j0) >> 2));
      float f[8];
      unpk8(q2, f);
#pragma unroll
      for (uint i = 0; i < 8u; ++i) {
        const float p = f[i] * Rr * cinv[i];
        const float h = fmaxf(p - dj[i] + MARGIN, 0.f) +
                        fmaxf(p - drow + MARGIN, 0.f);
        acc += (row == j0 + i) ? 0.f : h;
      }
    }
#pragma unroll
    for (int o = 32; o; o >>= 1) acc += __shfl_down(acc, o, 64);
    __syncthreads();  // red[] reuse
    if (lane == 0) red[w] = acc;
    __syncthreads();
    if (tid == 0) {
      float s = 0.f;
#pragma unroll
      for (uint i = 0; i < 16u; ++i) s += red[i];
      atomicAdd(out, s);
    }
  }
}

extern "C" void kernel_launch(void* const* d_in, const int* in_sizes, int n_in,
                              void* d_out, int out_size, void* d_ws,
                              size_t ws_size, hipStream_t stream) {
  const float* sims = (const float*)d_in[0];
  float* out = (float*)d_out;
  char* p = (char*)d_ws;
  uint* Qw = (uint*)p;                       p += (size_t)NN * NN;          // 64 MB
  float* part = (float*)p;                   p += (size_t)NBLK * NN * 4;    // 8 MB
  float* R = (float*)p;                      p += NN * 4;
  float* CsA = (float*)p;                    p += NN * 4;
  float* CsB = (float*)p;                    p += NN * 4;
  float* Qd = (float*)p;                     p += NN * 4;
  uint* ctl = (uint*)p;

  k_fused<<<NBLK, NTHR, 0, stream>>>(sims, Qw, part, R, CsA, CsB, Qd, ctl, out);
}